// Round 5
// baseline (115.775 us; speedup 1.0000x reference)
//
#include <hip/hip_runtime.h>
#include <cstdint>
#include <cstddef>

#define BB 4
#define NN 16384
#define SS 4096
#define CC 64
#define NSAMP 64
// radius*radius: python double 0.04000000000000000083 -> f32 compare -> 0.04f
#define R2 0.04f
#define PAD 67   // subtile row stride: write banks 2-way (free), read <=3-way

typedef float f32x4 __attribute__((ext_vector_type(4)));

// ---------------------------------------------------------------------------
// Kernel 1: transpose features (B,C,N) -> featT (B,N,C). 32 MB traffic ~6us.
// ---------------------------------------------------------------------------
__global__ __launch_bounds__(256) void transpose_feat(const float* __restrict__ f,
                                                      float* __restrict__ ft) {
    __shared__ float tile[64][65];
    int blk = blockIdx.x;
    int b   = blk / (NN / 64);
    int n0  = (blk % (NN / 64)) * 64;
    int t   = threadIdx.x;
    int nl  = t & 63;
    int cq  = t >> 6;
#pragma unroll
    for (int p = 0; p < 16; ++p) {
        int c = cq + p * 4;
        tile[c][nl] = f[((size_t)b * CC + c) * NN + n0 + nl];   // coalesced
    }
    __syncthreads();
#pragma unroll
    for (int p = 0; p < 16; ++p) {
        int nl2 = cq + p * 4;
        ft[((size_t)b * NN + n0 + nl2) * CC + nl] = tile[nl][nl2]; // coalesced
    }
}

// ---------------------------------------------------------------------------
// Kernel 2: fused ball-query + group, ONE QUERY PER WAVE, no __syncthreads.
// 256-thread blocks (4 independent waves) purely for occupancy packing.
// LDS: per-wave 16x67 subtile + 64-int compaction buffer = 18.2KB/block ->
// 8 blocks/CU -> 32 waves/CU. Grouping: 4 chunks of 16 samples, software-
// pipelined (next chunk's global gather issues before current chunk's LDS
// transpose + NT stores).
// ---------------------------------------------------------------------------
__global__ __launch_bounds__(256) void fused_qg(const float* __restrict__ xyz,
                                                const float* __restrict__ nxyz,
                                                const float* __restrict__ featT,
                                                float* __restrict__ out) {
    __shared__ float sub[4][16][PAD];
    __shared__ int   sidx[4][NSAMP];

    int t    = threadIdx.x;
    int wid  = t >> 6;
    int lane = t & 63;
    int wg   = blockIdx.x;
    // XCD swizzle: 4096 blocks (16384%8==0 bijective); each XCD gets a
    // contiguous half-batch -> featT slice ~4MB = one XCD L2.
    int qblk = (wg & 7) * (BB * SS / 8 / 4) + (wg >> 3);
    int q    = qblk * 4 + wid;
    int b    = q >> 12;
    int s    = q & (SS - 1);

    const float* xb = xyz + (size_t)b * NN * 3;
    float qx = nxyz[((size_t)b * SS + s) * 3 + 0];
    float qy = nxyz[((size_t)b * SS + s) * 3 + 1];
    float qz = nxyz[((size_t)b * SS + s) * 3 + 2];
    // q2 = (qx*qx + qy*qy) + qz*qz -- numpy f32 sequential, no FMA
    float q2 = __fadd_rn(__fadd_rn(__fmul_rn(qx, qx), __fmul_rn(qy, qy)),
                         __fmul_rn(qz, qz));

    // ---- phase 1: ball query (wave-private, 128 points/iter) ----
    int cnt = 0;
    float px0 = xb[lane * 3 + 0], py0 = xb[lane * 3 + 1], pz0 = xb[lane * 3 + 2];
    float px1 = xb[(lane + 64) * 3 + 0], py1 = xb[(lane + 64) * 3 + 1],
          pz1 = xb[(lane + 64) * 3 + 2];
    for (int base = 0; base < NN; base += 128) {
        float ax = px0, ay = py0, az = pz0;
        float bx = px1, by = py1, bz = pz1;
        int nb = base + 128;
        if (nb < NN) {   // uniform; prefetch next 128
            px0 = xb[(nb + lane) * 3 + 0];
            py0 = xb[(nb + lane) * 3 + 1];
            pz0 = xb[(nb + lane) * 3 + 2];
            px1 = xb[(nb + 64 + lane) * 3 + 0];
            py1 = xb[(nb + 64 + lane) * 3 + 1];
            pz1 = xb[(nb + 64 + lane) * 3 + 2];
        }
        // d2 = (q2 + p2) - (qp + qp), numpy-sequential f32
        float p2a = __fadd_rn(__fadd_rn(__fmul_rn(ax, ax), __fmul_rn(ay, ay)),
                              __fmul_rn(az, az));
        float qpa = __fadd_rn(__fadd_rn(__fmul_rn(qx, ax), __fmul_rn(qy, ay)),
                              __fmul_rn(qz, az));
        float d2a = __fsub_rn(__fadd_rn(q2, p2a), __fadd_rn(qpa, qpa));
        float p2b = __fadd_rn(__fadd_rn(__fmul_rn(bx, bx), __fmul_rn(by, by)),
                              __fmul_rn(bz, bz));
        float qpb = __fadd_rn(__fadd_rn(__fmul_rn(qx, bx), __fmul_rn(qy, by)),
                              __fmul_rn(qz, bz));
        float d2b = __fsub_rn(__fadd_rn(q2, p2b), __fadd_rn(qpb, qpb));
        bool in0 = d2a < R2;
        bool in1 = d2b < R2;
        unsigned long long m0 = __ballot(in0);
        unsigned long long m1 = __ballot(in1);
        int c0 = __popcll(m0);
        if (in0) {
            int pos = cnt + __popcll(m0 & ((1ull << lane) - 1ull));
            if (pos < NSAMP) sidx[wid][pos] = base + lane;
        }
        if (in1) {
            int pos = cnt + c0 + __popcll(m1 & ((1ull << lane) - 1ull));
            if (pos < NSAMP) sidx[wid][pos] = base + 64 + lane;
        }
        cnt += c0 + __popcll(m1);
        if (cnt >= NSAMP) break;   // uniform
    }
    // wave-synchronous LDS: drain ds ops before reading compaction buffer
    asm volatile("s_waitcnt lgkmcnt(0)" ::: "memory");
    int total = cnt < NSAMP ? cnt : NSAMP;
    int myidx = (total == 0) ? 0 : ((lane < total) ? sidx[wid][lane] : sidx[wid][0]);

    size_t obase = ((size_t)b * 67) * SS * 64 + (size_t)s * 64;
    size_t chs   = (size_t)SS * 64;

    // ---- grouped_xyz channels 0..2 ----
    {
        float gx = __fsub_rn(xb[(size_t)myidx * 3 + 0], qx);
        float gy = __fsub_rn(xb[(size_t)myidx * 3 + 1], qy);
        float gz = __fsub_rn(xb[(size_t)myidx * 3 + 2], qz);
        __builtin_nontemporal_store(gx, out + obase + 0 * chs + lane);
        __builtin_nontemporal_store(gy, out + obase + 1 * chs + lane);
        __builtin_nontemporal_store(gz, out + obase + 2 * chs + lane);
    }

    // ---- phase 2: features, 4 chunks of 16 samples, software-pipelined ----
    const float* ftb = featT + (size_t)b * NN * CC;
    int fc   = lane & 15;     // float4 column within a 64-ch row
    int rsub = lane >> 4;     // 0..3 (row group)
    int csub = lane >> 2;     // 0..15 (store channel sub)
    int s4   = lane & 3;      // 0..3 (store sample-f4 sub)

    f32x4 v[4];
#pragma unroll
    for (int j = 0; j < 4; ++j) {          // prologue: gather chunk 0
        int row = j * 4 + rsub;
        int pr  = __shfl(myidx, row);
        v[j] = *(const f32x4*)(ftb + (size_t)pr * CC + fc * 4);
    }
#pragma unroll
    for (int chunk = 0; chunk < 4; ++chunk) {
        f32x4 w[4];
        if (chunk < 3) {                   // gather next chunk early
#pragma unroll
            for (int j = 0; j < 4; ++j) {
                int row = (chunk + 1) * 16 + j * 4 + rsub;
                int pr  = __shfl(myidx, row);
                w[j] = *(const f32x4*)(ftb + (size_t)pr * CC + fc * 4);
            }
        }
        // write current chunk rows into per-wave subtile
#pragma unroll
        for (int j = 0; j < 4; ++j) {
            int r = j * 4 + rsub;
            sub[wid][r][fc * 4 + 0] = v[j].x;
            sub[wid][r][fc * 4 + 1] = v[j].y;
            sub[wid][r][fc * 4 + 2] = v[j].z;
            sub[wid][r][fc * 4 + 3] = v[j].w;
        }
        asm volatile("s_waitcnt lgkmcnt(0)" ::: "memory");  // wave-sync LDS
        // transposed read + coalesced NT stores (16ch x 64B per instr)
#pragma unroll
        for (int j = 0; j < 4; ++j) {
            int c = j * 16 + csub;
            f32x4 o;
            o.x = sub[wid][s4 * 4 + 0][c];
            o.y = sub[wid][s4 * 4 + 1][c];
            o.z = sub[wid][s4 * 4 + 2][c];
            o.w = sub[wid][s4 * 4 + 3][c];
            __builtin_nontemporal_store(o,
                (f32x4*)(out + obase + (size_t)(3 + c) * chs + chunk * 16 + s4 * 4));
        }
        // reads complete before next chunk's writes (in-order DS per wave);
        // conservative drain anyway:
        asm volatile("s_waitcnt lgkmcnt(0)" ::: "memory");
#pragma unroll
        for (int j = 0; j < 4; ++j) v[j] = w[j];
    }
}

// ---------------------------------------------------------------------------
// Fallback (ws too small): fused one-wave-per-query, direct (C,N) gather.
// ---------------------------------------------------------------------------
__global__ __launch_bounds__(64) void qg_fallback(const float* __restrict__ xyz,
                                                  const float* __restrict__ nxyz,
                                                  const float* __restrict__ feat,
                                                  float* __restrict__ out) {
    __shared__ int sidx[NSAMP];
    int q = blockIdx.x;
    int b = q >> 12, s = q & (SS - 1);
    int lane = threadIdx.x;
    const float* xb = xyz + (size_t)b * NN * 3;
    float qx = nxyz[((size_t)b * SS + s) * 3 + 0];
    float qy = nxyz[((size_t)b * SS + s) * 3 + 1];
    float qz = nxyz[((size_t)b * SS + s) * 3 + 2];
    float q2 = __fadd_rn(__fadd_rn(__fmul_rn(qx, qx), __fmul_rn(qy, qy)),
                         __fmul_rn(qz, qz));
    int cnt = 0;
    for (int base = 0; base < NN; base += 64) {
        float cx = xb[(size_t)(base + lane) * 3 + 0];
        float cy = xb[(size_t)(base + lane) * 3 + 1];
        float cz = xb[(size_t)(base + lane) * 3 + 2];
        float p2 = __fadd_rn(__fadd_rn(__fmul_rn(cx, cx), __fmul_rn(cy, cy)),
                             __fmul_rn(cz, cz));
        float qp = __fadd_rn(__fadd_rn(__fmul_rn(qx, cx), __fmul_rn(qy, cy)),
                             __fmul_rn(qz, cz));
        float d2 = __fsub_rn(__fadd_rn(q2, p2), __fadd_rn(qp, qp));
        bool in = d2 < R2;
        unsigned long long m = __ballot(in);
        if (in) {
            int pos = cnt + __popcll(m & ((1ull << lane) - 1ull));
            if (pos < NSAMP) sidx[pos] = base + lane;
        }
        cnt += __popcll(m);
        if (cnt >= NSAMP) break;
    }
    __syncthreads();
    int total = cnt < NSAMP ? cnt : NSAMP;
    int myidx = (total == 0) ? 0 : ((lane < total) ? sidx[lane] : sidx[0]);
    size_t obase = ((size_t)b * 67) * SS * 64 + (size_t)s * 64;
    size_t chs   = (size_t)SS * 64;
    out[obase + 0 * chs + lane] = __fsub_rn(xb[(size_t)myidx * 3 + 0], qx);
    out[obase + 1 * chs + lane] = __fsub_rn(xb[(size_t)myidx * 3 + 1], qy);
    out[obase + 2 * chs + lane] = __fsub_rn(xb[(size_t)myidx * 3 + 2], qz);
    const float* fb = feat + (size_t)b * CC * NN;
#pragma unroll 4
    for (int c = 0; c < CC; ++c)
        out[obase + (size_t)(3 + c) * chs + lane] = fb[(size_t)c * NN + myidx];
}

// ---------------------------------------------------------------------------
extern "C" void kernel_launch(void* const* d_in, const int* in_sizes, int n_in,
                              void* d_out, int out_size, void* d_ws, size_t ws_size,
                              hipStream_t stream) {
    const float* xyz  = (const float*)d_in[0];   // (B,N,3)
    const float* nxyz = (const float*)d_in[1];   // (B,S,3)
    const float* feat = (const float*)d_in[2];   // (B,C,N)
    float* out = (float*)d_out;                  // (B,67,S,64)

    size_t needT = (size_t)BB * NN * CC * sizeof(float);   // 16 MB
    if (ws_size >= needT) {
        float* featT = (float*)d_ws;
        transpose_feat<<<BB * (NN / 64), 256, 0, stream>>>(feat, featT);
        fused_qg<<<BB * SS / 4, 256, 0, stream>>>(xyz, nxyz, featT, out);
    } else {
        qg_fallback<<<BB * SS, 64, 0, stream>>>(xyz, nxyz, feat, out);
    }
}

// Round 7
// 83.004 us; speedup vs baseline: 1.3948x; 1.3948x over previous
//
#include <hip/hip_runtime.h>
#include <cstdint>
#include <cstddef>

#define BB 4
#define NN 16384
#define SS 4096
#define CC 64
#define NSAMP 64
// radius*radius: python double 0.04000000000000000083 -> f32 compare -> 0.04f
#define R2 0.04f

#define TRANS_BLOCKS (BB * (NN / 64))          // 1024
#define XYZW_BLOCKS  64                        // stride loop covers B*N points

typedef float f32x4 __attribute__((ext_vector_type(4)));

// ---------------------------------------------------------------------------
// Kernel 1 (prep): blocks [0,1024) transpose features (B,C,N)->(B,N,C);
// blocks [1024,1088) pack xyzw[p] = (x,y,z,0) -- pure data movement, no
// arithmetic (p2 stays inline in the scan, bit-identical to R4).
// ---------------------------------------------------------------------------
__global__ __launch_bounds__(256) void prep_kernel(const float* __restrict__ xyz,
                                                   const float* __restrict__ feat,
                                                   float* __restrict__ featT,
                                                   f32x4* __restrict__ xyzw) {
    int t = threadIdx.x;
    if (blockIdx.x < TRANS_BLOCKS) {
        __shared__ float tile[64][65];
        int blk = blockIdx.x;
        int b   = blk / (NN / 64);
        int n0  = (blk % (NN / 64)) * 64;
        int nl  = t & 63;
        int cq  = t >> 6;
#pragma unroll
        for (int p = 0; p < 16; ++p) {
            int c = cq + p * 4;
            tile[c][nl] = feat[((size_t)b * CC + c) * NN + n0 + nl];   // coalesced
        }
        __syncthreads();
#pragma unroll
        for (int p = 0; p < 16; ++p) {
            int nl2 = cq + p * 4;
            featT[((size_t)b * NN + n0 + nl2) * CC + nl] = tile[nl][nl2]; // coalesced
        }
        return;
    }
    // ---- xyzw pack: grid-stride over all B*N points, scalar reads ----
    int T0     = (blockIdx.x - TRANS_BLOCKS) * 256 + t;
    int stride = XYZW_BLOCKS * 256;            // 16384
    for (int p = T0; p < BB * NN; p += stride) {
        float x = xyz[(size_t)p * 3 + 0];
        float y = xyz[(size_t)p * 3 + 1];
        float z = xyz[(size_t)p * 3 + 2];
        f32x4 o = {x, y, z, 0.0f};
        xyzw[p] = o;
    }
}

// ---------------------------------------------------------------------------
// Kernel 2: fused ball-query + group (R4 structure, R4 arithmetic).
// 256 threads = 4 waves, 4 queries/block: per-wave scan (128 pts/iter,
// one dwordx4 load per point), then block-cooperative grouping through one
// 64x65 LDS tile, sequential over 4 queries. 17.7KB LDS -> 32 waves/CU.
// ---------------------------------------------------------------------------
__global__ __launch_bounds__(256) void fused_qg(const f32x4* __restrict__ xyzw,
                                                const float* __restrict__ nxyz,
                                                const float* __restrict__ featT,
                                                float* __restrict__ out) {
    __shared__ float tile[64][65];
    __shared__ int   sidx[4][NSAMP];

    int t    = threadIdx.x;
    int wid  = t >> 6;
    int lane = t & 63;
    int wg   = blockIdx.x;
    // XCD swizzle: 4096 blocks (%8==0 bijective); each XCD gets a contiguous
    // half-batch -> featT slice ~4MB = one XCD L2.
    int qblk = (wg & 7) * (BB * SS / 8 / 4) + (wg >> 3);
    int q0   = qblk * 4;

    // ---- phase 1: ball query, one query per wave ----
    {
        int q = q0 + wid;
        int b = q >> 12;
        int s = q & (SS - 1);
        const f32x4* xp = xyzw + (size_t)b * NN;
        float qx = nxyz[((size_t)b * SS + s) * 3 + 0];
        float qy = nxyz[((size_t)b * SS + s) * 3 + 1];
        float qz = nxyz[((size_t)b * SS + s) * 3 + 2];
        // q2 = (qx*qx + qy*qy) + qz*qz -- numpy f32 sequential, no FMA
        float q2 = __fadd_rn(__fadd_rn(__fmul_rn(qx, qx), __fmul_rn(qy, qy)),
                             __fadd_rn(__fmul_rn(qz, qz), 0.0f) == __fmul_rn(qz, qz)
                                 ? __fmul_rn(qz, qz) : __fmul_rn(qz, qz));
        // (the ternary above is identity; keep plain form:)
        q2 = __fadd_rn(__fadd_rn(__fmul_rn(qx, qx), __fmul_rn(qy, qy)),
                       __fmul_rn(qz, qz));

        int cnt = 0;
        f32x4 A  = xp[lane];
        f32x4 Bv = xp[lane + 64];
        for (int base = 0; base < NN; base += 128) {
            f32x4 ca = A, cb = Bv;
            int nb = base + 128;
            if (nb < NN) {            // uniform; prefetch next 128
                A  = xp[nb + lane];
                Bv = xp[nb + 64 + lane];
            }
            // d2 = (q2 + p2) - (qp + qp), numpy-sequential f32 (R4-identical)
            float p2a = __fadd_rn(__fadd_rn(__fmul_rn(ca.x, ca.x), __fmul_rn(ca.y, ca.y)),
                                  __fmul_rn(ca.z, ca.z));
            float qpa = __fadd_rn(__fadd_rn(__fmul_rn(qx, ca.x), __fmul_rn(qy, ca.y)),
                                  __fmul_rn(qz, ca.z));
            float d2a = __fsub_rn(__fadd_rn(q2, p2a), __fadd_rn(qpa, qpa));
            float p2b = __fadd_rn(__fadd_rn(__fmul_rn(cb.x, cb.x), __fmul_rn(cb.y, cb.y)),
                                  __fmul_rn(cb.z, cb.z));
            float qpb = __fadd_rn(__fadd_rn(__fmul_rn(qx, cb.x), __fmul_rn(qy, cb.y)),
                                  __fmul_rn(qz, cb.z));
            float d2b = __fsub_rn(__fadd_rn(q2, p2b), __fadd_rn(qpb, qpb));
            bool in0 = d2a < R2;
            bool in1 = d2b < R2;
            unsigned long long m0 = __ballot(in0);
            unsigned long long m1 = __ballot(in1);
            int c0 = __popcll(m0);
            if (in0) {
                int pos = cnt + __popcll(m0 & ((1ull << lane) - 1ull));
                if (pos < NSAMP) sidx[wid][pos] = base + lane;
            }
            if (in1) {
                int pos = cnt + c0 + __popcll(m1 & ((1ull << lane) - 1ull));
                if (pos < NSAMP) sidx[wid][pos] = base + 64 + lane;
            }
            cnt += c0 + __popcll(m1);
            if (cnt >= NSAMP) break;  // uniform
        }
        // wave-synchronous LDS: drain ds ops before reading compaction buffer
        asm volatile("s_waitcnt lgkmcnt(0)" ::: "memory");
        int total = cnt < NSAMP ? cnt : NSAMP;
        int myidx = (total == 0) ? 0 : ((lane < total) ? sidx[wid][lane] : sidx[wid][0]);
        asm volatile("s_waitcnt lgkmcnt(0)" ::: "memory");
        sidx[wid][lane] = myidx;      // normalized (first-index-filled) list
    }
    __syncthreads();

    // ---- phase 2: grouping, 4 queries sequentially, whole block each ----
    int rsub = t >> 4;       // 0..15 (gather row sub-index)
    int cf4  = t & 15;       // 0..15 (float4 column)
    int k4   = t & 15;       // store: sample/4 index
#pragma unroll
    for (int qi = 0; qi < 4; ++qi) {
        int q = q0 + qi;
        int b = q >> 12;
        int s = q & (SS - 1);
        const float* ftb = featT + (size_t)b * NN * CC;
        // gather 64 rows x 64 ch into tile (coalesced 256B per 16-lane group)
#pragma unroll
        for (int j = 0; j < 4; ++j) {
            int row = j * 16 + rsub;
            int pr  = sidx[qi][row];
            const f32x4 v = *(const f32x4*)(ftb + (size_t)pr * CC + cf4 * 4);
            tile[row][cf4 * 4 + 0] = v.x;
            tile[row][cf4 * 4 + 1] = v.y;
            tile[row][cf4 * 4 + 2] = v.z;
            tile[row][cf4 * 4 + 3] = v.w;
        }
        size_t obase = ((size_t)b * 67) * SS * 64 + (size_t)s * 64;
        size_t chs   = (size_t)SS * 64;
        // xyz channels 0..2: handled by wave qi (one dwordx4 load per lane)
        if (wid == qi) {
            int id = sidx[qi][lane];
            float qx = nxyz[((size_t)b * SS + s) * 3 + 0];
            float qy = nxyz[((size_t)b * SS + s) * 3 + 1];
            float qz = nxyz[((size_t)b * SS + s) * 3 + 2];
            const f32x4 P = xyzw[(size_t)b * NN + id];
            float gx = __fsub_rn(P.x, qx);
            float gy = __fsub_rn(P.y, qy);
            float gz = __fsub_rn(P.z, qz);
            __builtin_nontemporal_store(gx, out + obase + 0 * chs + lane);
            __builtin_nontemporal_store(gy, out + obase + 1 * chs + lane);
            __builtin_nontemporal_store(gz, out + obase + 2 * chs + lane);
        }
        __syncthreads();
        // feature channels 3..66: transposed tile reads, coalesced NT stores
#pragma unroll
        for (int j = 0; j < 4; ++j) {
            int c = j * 16 + (t >> 4);
            f32x4 o;
            o.x = tile[k4 * 4 + 0][c];
            o.y = tile[k4 * 4 + 1][c];
            o.z = tile[k4 * 4 + 2][c];
            o.w = tile[k4 * 4 + 3][c];
            __builtin_nontemporal_store(o,
                (f32x4*)(out + obase + (size_t)(3 + c) * chs + k4 * 4));
        }
        __syncthreads();   // protect tile before next query overwrites
    }
}

// ---------------------------------------------------------------------------
// Fallback (ws too small): fused one-wave-per-query, direct (C,N) gather.
// ---------------------------------------------------------------------------
__global__ __launch_bounds__(64) void qg_fallback(const float* __restrict__ xyz,
                                                  const float* __restrict__ nxyz,
                                                  const float* __restrict__ feat,
                                                  float* __restrict__ out) {
    __shared__ int sidx[NSAMP];
    int q = blockIdx.x;
    int b = q >> 12, s = q & (SS - 1);
    int lane = threadIdx.x;
    const float* xb = xyz + (size_t)b * NN * 3;
    float qx = nxyz[((size_t)b * SS + s) * 3 + 0];
    float qy = nxyz[((size_t)b * SS + s) * 3 + 1];
    float qz = nxyz[((size_t)b * SS + s) * 3 + 2];
    float q2 = __fadd_rn(__fadd_rn(__fmul_rn(qx, qx), __fmul_rn(qy, qy)),
                         __fmul_rn(qz, qz));
    int cnt = 0;
    for (int base = 0; base < NN; base += 64) {
        float cx = xb[(size_t)(base + lane) * 3 + 0];
        float cy = xb[(size_t)(base + lane) * 3 + 1];
        float cz = xb[(size_t)(base + lane) * 3 + 2];
        float p2 = __fadd_rn(__fadd_rn(__fmul_rn(cx, cx), __fmul_rn(cy, cy)),
                             __fmul_rn(cz, cz));
        float qp = __fadd_rn(__fadd_rn(__fmul_rn(qx, cx), __fmul_rn(qy, cy)),
                             __fmul_rn(qz, cz));
        float d2 = __fsub_rn(__fadd_rn(q2, p2), __fadd_rn(qp, qp));
        bool in = d2 < R2;
        unsigned long long m = __ballot(in);
        if (in) {
            int pos = cnt + __popcll(m & ((1ull << lane) - 1ull));
            if (pos < NSAMP) sidx[pos] = base + lane;
        }
        cnt += __popcll(m);
        if (cnt >= NSAMP) break;
    }
    __syncthreads();
    int total = cnt < NSAMP ? cnt : NSAMP;
    int myidx = (total == 0) ? 0 : ((lane < total) ? sidx[lane] : sidx[0]);
    size_t obase = ((size_t)b * 67) * SS * 64 + (size_t)s * 64;
    size_t chs   = (size_t)SS * 64;
    out[obase + 0 * chs + lane] = __fsub_rn(xb[(size_t)myidx * 3 + 0], qx);
    out[obase + 1 * chs + lane] = __fsub_rn(xb[(size_t)myidx * 3 + 1], qy);
    out[obase + 2 * chs + lane] = __fsub_rn(xb[(size_t)myidx * 3 + 2], qz);
    const float* fb = feat + (size_t)b * CC * NN;
#pragma unroll 4
    for (int c = 0; c < CC; ++c)
        out[obase + (size_t)(3 + c) * chs + lane] = fb[(size_t)c * NN + myidx];
}

// ---------------------------------------------------------------------------
extern "C" void kernel_launch(void* const* d_in, const int* in_sizes, int n_in,
                              void* d_out, int out_size, void* d_ws, size_t ws_size,
                              hipStream_t stream) {
    const float* xyz  = (const float*)d_in[0];   // (B,N,3)
    const float* nxyz = (const float*)d_in[1];   // (B,S,3)
    const float* feat = (const float*)d_in[2];   // (B,C,N)
    float* out = (float*)d_out;                  // (B,67,S,64)

    size_t needT = (size_t)BB * NN * CC * sizeof(float);        // 16 MB
    size_t needW = (size_t)BB * NN * 4 * sizeof(float);         //  1 MB
    if (ws_size >= needT + needW) {
        float* featT = (float*)d_ws;
        f32x4* xyzw  = (f32x4*)((char*)d_ws + needT);
        prep_kernel<<<TRANS_BLOCKS + XYZW_BLOCKS, 256, 0, stream>>>(xyz, feat,
                                                                    featT, xyzw);
        fused_qg<<<BB * SS / 4, 256, 0, stream>>>(xyzw, nxyz, featT, out);
    } else {
        qg_fallback<<<BB * SS, 64, 0, stream>>>(xyz, nxyz, feat, out);
    }
}

// Round 8
// 80.327 us; speedup vs baseline: 1.4413x; 1.0333x over previous
//
#include <hip/hip_runtime.h>
#include <cstdint>
#include <cstddef>

#define BB 4
#define NN 16384
#define SS 4096
#define CC 64
#define NSAMP 64
// radius*radius: python double 0.04000000000000000083 -> f32 compare -> 0.04f
#define R2 0.04f

#define TRANS_BLOCKS (BB * (NN / 64))          // 1024
#define XYZW_BLOCKS  64

typedef float f32x4 __attribute__((ext_vector_type(4)));

// ---------------------------------------------------------------------------
// Kernel 1 (prep): blocks [0,1024) transpose features (B,C,N)->(B,N,C);
// blocks [1024,1088) pack xyzw[p] = (x,y,z,0) (pure data movement).
// ---------------------------------------------------------------------------
__global__ __launch_bounds__(256) void prep_kernel(const float* __restrict__ xyz,
                                                   const float* __restrict__ feat,
                                                   float* __restrict__ featT,
                                                   f32x4* __restrict__ xyzw) {
    int t = threadIdx.x;
    if (blockIdx.x < TRANS_BLOCKS) {
        __shared__ float tile[64][65];
        int blk = blockIdx.x;
        int b   = blk / (NN / 64);
        int n0  = (blk % (NN / 64)) * 64;
        int nl  = t & 63;
        int cq  = t >> 6;
#pragma unroll
        for (int p = 0; p < 16; ++p) {
            int c = cq + p * 4;
            tile[c][nl] = feat[((size_t)b * CC + c) * NN + n0 + nl];   // coalesced
        }
        __syncthreads();
#pragma unroll
        for (int p = 0; p < 16; ++p) {
            int nl2 = cq + p * 4;
            featT[((size_t)b * NN + n0 + nl2) * CC + nl] = tile[nl][nl2]; // coalesced
        }
        return;
    }
    // ---- xyzw pack: grid-stride, scalar reads (no swizzle logic) ----
    int T0     = (blockIdx.x - TRANS_BLOCKS) * 256 + t;
    int stride = XYZW_BLOCKS * 256;
    for (int p = T0; p < BB * NN; p += stride) {
        float x = xyz[(size_t)p * 3 + 0];
        float y = xyz[(size_t)p * 3 + 1];
        float z = xyz[(size_t)p * 3 + 2];
        f32x4 o = {x, y, z, 0.0f};
        xyzw[p] = o;
    }
}

// ---------------------------------------------------------------------------
// Kernel 2: fused ball-query + group, ONE QUERY PER WAVE end-to-end, zero
// block barriers. Scan identical to R7. Grouping: 4 chunks of 16 channels;
// per chunk the wave gathers 64 rows x 16ch (64B per 4-lane row group) into
// a private 64x17 LDS subtile, then stores 4x256B NT segments per instr
// (R4's store geometry). Chunk gathers software-pipelined. LDS 18.4KB/block
// -> 8 blocks/CU -> 32 waves/CU.
// ---------------------------------------------------------------------------
__global__ __launch_bounds__(256) void fused_qg(const f32x4* __restrict__ xyzw,
                                                const float* __restrict__ nxyz,
                                                const float* __restrict__ featT,
                                                float* __restrict__ out) {
    __shared__ float sub[4][64][17];   // per-wave 64 samples x 16ch (+1 pad)
    __shared__ int   sidx[4][NSAMP];

    int t    = threadIdx.x;
    int wid  = t >> 6;
    int lane = t & 63;
    int wg   = blockIdx.x;
    // XCD swizzle: 4096 blocks (%8==0 bijective); each XCD gets a contiguous
    // half-batch -> featT slice ~4MB = one XCD L2.
    int qblk = (wg & 7) * (BB * SS / 8 / 4) + (wg >> 3);
    int q    = qblk * 4 + wid;
    int b    = q >> 12;
    int s    = q & (SS - 1);

    const f32x4* xp = xyzw + (size_t)b * NN;
    float qx = nxyz[((size_t)b * SS + s) * 3 + 0];
    float qy = nxyz[((size_t)b * SS + s) * 3 + 1];
    float qz = nxyz[((size_t)b * SS + s) * 3 + 2];
    // q2 = (qx*qx + qy*qy) + qz*qz -- numpy f32 sequential, no FMA
    float q2 = __fadd_rn(__fadd_rn(__fmul_rn(qx, qx), __fmul_rn(qy, qy)),
                         __fmul_rn(qz, qz));

    // ---- phase 1: ball query (wave-private, 128 pts/iter, dwordx4 loads) ----
    int cnt = 0;
    f32x4 A  = xp[lane];
    f32x4 Bv = xp[lane + 64];
    for (int base = 0; base < NN; base += 128) {
        f32x4 ca = A, cb = Bv;
        int nb = base + 128;
        if (nb < NN) {            // uniform; prefetch next 128
            A  = xp[nb + lane];
            Bv = xp[nb + 64 + lane];
        }
        // d2 = (q2 + p2) - (qp + qp), numpy-sequential f32 (R4-identical)
        float p2a = __fadd_rn(__fadd_rn(__fmul_rn(ca.x, ca.x), __fmul_rn(ca.y, ca.y)),
                              __fmul_rn(ca.z, ca.z));
        float qpa = __fadd_rn(__fadd_rn(__fmul_rn(qx, ca.x), __fmul_rn(qy, ca.y)),
                              __fmul_rn(qz, ca.z));
        float d2a = __fsub_rn(__fadd_rn(q2, p2a), __fadd_rn(qpa, qpa));
        float p2b = __fadd_rn(__fadd_rn(__fmul_rn(cb.x, cb.x), __fmul_rn(cb.y, cb.y)),
                              __fmul_rn(cb.z, cb.z));
        float qpb = __fadd_rn(__fadd_rn(__fmul_rn(qx, cb.x), __fmul_rn(qy, cb.y)),
                              __fmul_rn(qz, cb.z));
        float d2b = __fsub_rn(__fadd_rn(q2, p2b), __fadd_rn(qpb, qpb));
        bool in0 = d2a < R2;
        bool in1 = d2b < R2;
        unsigned long long m0 = __ballot(in0);
        unsigned long long m1 = __ballot(in1);
        int c0 = __popcll(m0);
        if (in0) {
            int pos = cnt + __popcll(m0 & ((1ull << lane) - 1ull));
            if (pos < NSAMP) sidx[wid][pos] = base + lane;
        }
        if (in1) {
            int pos = cnt + c0 + __popcll(m1 & ((1ull << lane) - 1ull));
            if (pos < NSAMP) sidx[wid][pos] = base + 64 + lane;
        }
        cnt += c0 + __popcll(m1);
        if (cnt >= NSAMP) break;  // uniform
    }
    // wave-synchronous LDS: drain ds ops before reading compaction buffer
    asm volatile("s_waitcnt lgkmcnt(0)" ::: "memory");
    int total = cnt < NSAMP ? cnt : NSAMP;
    int myidx = (total == 0) ? 0 : ((lane < total) ? sidx[wid][lane] : sidx[wid][0]);
    asm volatile("s_waitcnt lgkmcnt(0)" ::: "memory");
    sidx[wid][lane] = myidx;      // normalized (first-index-filled) list
    asm volatile("s_waitcnt lgkmcnt(0)" ::: "memory");

    size_t obase = ((size_t)b * 67) * SS * 64 + (size_t)s * 64;
    size_t chs   = (size_t)SS * 64;

    // ---- grouped_xyz channels 0..2 ----
    {
        const f32x4 P = xp[myidx];
        float gx = __fsub_rn(P.x, qx);
        float gy = __fsub_rn(P.y, qy);
        float gz = __fsub_rn(P.z, qz);
        __builtin_nontemporal_store(gx, out + obase + 0 * chs + lane);
        __builtin_nontemporal_store(gy, out + obase + 1 * chs + lane);
        __builtin_nontemporal_store(gz, out + obase + 2 * chs + lane);
    }

    // ---- phase 2: features, 4 chunks of 16 channels, pipelined ----
    const float* ftb = featT + (size_t)b * NN * CC;
    int r4 = lane >> 2;       // 0..15: row sub-index for gather
    int fc = lane & 3;        // 0..3 : f32x4 within the 16-channel chunk
    int k4 = lane & 15;       // 0..15: sample/4 index for store
    int cs = lane >> 4;       // 0..3 : channel sub-index for store

    int ridx[4];
#pragma unroll
    for (int j = 0; j < 4; ++j) ridx[j] = sidx[wid][j * 16 + r4];
    asm volatile("s_waitcnt lgkmcnt(0)" ::: "memory");

    f32x4 v[4];
#pragma unroll
    for (int j = 0; j < 4; ++j)        // prologue: gather chunk 0
        v[j] = *(const f32x4*)(ftb + (size_t)ridx[j] * CC + fc * 4);

#pragma unroll
    for (int h = 0; h < 4; ++h) {
        f32x4 w[4];
        if (h < 3) {                   // prefetch next chunk's gathers
#pragma unroll
            for (int j = 0; j < 4; ++j)
                w[j] = *(const f32x4*)(ftb + (size_t)ridx[j] * CC + (h + 1) * 16 + fc * 4);
        }
        // stage current chunk into private subtile (2-way banks = free)
#pragma unroll
        for (int j = 0; j < 4; ++j) {
            int row = j * 16 + r4;
            sub[wid][row][fc * 4 + 0] = v[j].x;
            sub[wid][row][fc * 4 + 1] = v[j].y;
            sub[wid][row][fc * 4 + 2] = v[j].z;
            sub[wid][row][fc * 4 + 3] = v[j].w;
        }
        asm volatile("s_waitcnt lgkmcnt(0)" ::: "memory");  // wave-sync LDS
        // store: per instr 4 channels x 256B contiguous segments
#pragma unroll
        for (int j = 0; j < 4; ++j) {
            int cc = j * 4 + cs;              // channel within chunk
            int c  = h * 16 + cc;             // global feature channel
            f32x4 o;
            o.x = sub[wid][k4 * 4 + 0][cc];
            o.y = sub[wid][k4 * 4 + 1][cc];
            o.z = sub[wid][k4 * 4 + 2][cc];
            o.w = sub[wid][k4 * 4 + 3][cc];
            __builtin_nontemporal_store(o,
                (f32x4*)(out + obase + (size_t)(3 + c) * chs + k4 * 4));
        }
        asm volatile("s_waitcnt lgkmcnt(0)" ::: "memory");  // reads done before overwrite
#pragma unroll
        for (int j = 0; j < 4; ++j) v[j] = w[j];
    }
}

// ---------------------------------------------------------------------------
// Fallback (ws too small): fused one-wave-per-query, direct (C,N) gather.
// ---------------------------------------------------------------------------
__global__ __launch_bounds__(64) void qg_fallback(const float* __restrict__ xyz,
                                                  const float* __restrict__ nxyz,
                                                  const float* __restrict__ feat,
                                                  float* __restrict__ out) {
    __shared__ int sidx[NSAMP];
    int q = blockIdx.x;
    int b = q >> 12, s = q & (SS - 1);
    int lane = threadIdx.x;
    const float* xb = xyz + (size_t)b * NN * 3;
    float qx = nxyz[((size_t)b * SS + s) * 3 + 0];
    float qy = nxyz[((size_t)b * SS + s) * 3 + 1];
    float qz = nxyz[((size_t)b * SS + s) * 3 + 2];
    float q2 = __fadd_rn(__fadd_rn(__fmul_rn(qx, qx), __fmul_rn(qy, qy)),
                         __fmul_rn(qz, qz));
    int cnt = 0;
    for (int base = 0; base < NN; base += 64) {
        float cx = xb[(size_t)(base + lane) * 3 + 0];
        float cy = xb[(size_t)(base + lane) * 3 + 1];
        float cz = xb[(size_t)(base + lane) * 3 + 2];
        float p2 = __fadd_rn(__fadd_rn(__fmul_rn(cx, cx), __fmul_rn(cy, cy)),
                             __fmul_rn(cz, cz));
        float qp = __fadd_rn(__fadd_rn(__fmul_rn(qx, cx), __fmul_rn(qy, cy)),
                             __fmul_rn(qz, cz));
        float d2 = __fsub_rn(__fadd_rn(q2, p2), __fadd_rn(qp, qp));
        bool in = d2 < R2;
        unsigned long long m = __ballot(in);
        if (in) {
            int pos = cnt + __popcll(m & ((1ull << lane) - 1ull));
            if (pos < NSAMP) sidx[pos] = base + lane;
        }
        cnt += __popcll(m);
        if (cnt >= NSAMP) break;
    }
    __syncthreads();
    int total = cnt < NSAMP ? cnt : NSAMP;
    int myidx = (total == 0) ? 0 : ((lane < total) ? sidx[lane] : sidx[0]);
    size_t obase = ((size_t)b * 67) * SS * 64 + (size_t)s * 64;
    size_t chs   = (size_t)SS * 64;
    out[obase + 0 * chs + lane] = __fsub_rn(xb[(size_t)myidx * 3 + 0], qx);
    out[obase + 1 * chs + lane] = __fsub_rn(xb[(size_t)myidx * 3 + 1], qy);
    out[obase + 2 * chs + lane] = __fsub_rn(xb[(size_t)myidx * 3 + 2], qz);
    const float* fb = feat + (size_t)b * CC * NN;
#pragma unroll 4
    for (int c = 0; c < CC; ++c)
        out[obase + (size_t)(3 + c) * chs + lane] = fb[(size_t)c * NN + myidx];
}

// ---------------------------------------------------------------------------
extern "C" void kernel_launch(void* const* d_in, const int* in_sizes, int n_in,
                              void* d_out, int out_size, void* d_ws, size_t ws_size,
                              hipStream_t stream) {
    const float* xyz  = (const float*)d_in[0];   // (B,N,3)
    const float* nxyz = (const float*)d_in[1];   // (B,S,3)
    const float* feat = (const float*)d_in[2];   // (B,C,N)
    float* out = (float*)d_out;                  // (B,67,S,64)

    size_t needT = (size_t)BB * NN * CC * sizeof(float);        // 16 MB
    size_t needW = (size_t)BB * NN * 4 * sizeof(float);         //  1 MB
    if (ws_size >= needT + needW) {
        float* featT = (float*)d_ws;
        f32x4* xyzw  = (f32x4*)((char*)d_ws + needT);
        prep_kernel<<<TRANS_BLOCKS + XYZW_BLOCKS, 256, 0, stream>>>(xyz, feat,
                                                                    featT, xyzw);
        fused_qg<<<BB * SS / 4, 256, 0, stream>>>(xyzw, nxyz, featT, out);
    } else {
        qg_fallback<<<BB * SS, 64, 0, stream>>>(xyz, nxyz, feat, out);
    }
}